// Round 6
// baseline (157.071 us; speedup 1.0000x reference)
//
#include <hip/hip_runtime.h>
#include <math.h>

#define NATOMS 512
#define TPB 256
#define WPB 4  // waves per block; one wave handles one batch element
#define FPE (3 * NATOMS)

// Packed 12-byte atom record; align 4 so addresses base+12*A are valid.
struct __attribute__((aligned(4))) F3 { float x, y, z; };

// ---------------- Kernel 1: streaming reduction ----------------
// One 64-lane wave per batch element. Lane l handles atoms 64k+l (k=0..7),
// 12 B lane stride. Two load/accumulate phases of 4 atoms keep peak live
// registers ~48 so __launch_bounds__(256,8) (VGPR<=64) holds -> 32 waves/CU,
// entire 2048-block grid co-resident in one generation (no tail).
__global__ __launch_bounds__(TPB, 8) void kabsch_reduce_kernel(
    const float* __restrict__ inp,
    const float* __restrict__ tgt,
    const int* __restrict__ num_atoms,
    float* __restrict__ partial,   // [B][16]
    int B)
{
    const int wave = threadIdx.x >> 6;
    const int lane = threadIdx.x & 63;
    const int b = blockIdx.x * WPB + wave;
    if (b >= B) return;

    const int na = num_atoms[b];

    const F3* sA = (const F3*)(inp + (size_t)b * FPE);
    const F3* dA = (const F3*)(tgt + (size_t)b * FPE);

    float v[16];
    #pragma unroll
    for (int i = 0; i < 16; ++i) v[i] = 0.f;

    #pragma unroll
    for (int phase = 0; phase < 2; ++phase) {
        F3 S[4], D[4];
        #pragma unroll
        for (int k = 0; k < 4; ++k) {
            const int atom = 64 * (4 * phase + k) + lane;
            S[k] = sA[atom];
            D[k] = dA[atom];
        }
        #pragma unroll
        for (int k = 0; k < 4; ++k) {
            const int atom = 64 * (4 * phase + k) + lane;
            const float m = (atom < na) ? 1.f : 0.f;
            const float sx = S[k].x * m;
            const float sy = S[k].y * m;
            const float sz = S[k].z * m;
            const float dx = D[k].x * m;
            const float dy = D[k].y * m;
            const float dz = D[k].z * m;
            v[0]  += sx * dx;  v[1]  += sx * dy;  v[2]  += sx * dz;
            v[3]  += sy * dx;  v[4]  += sy * dy;  v[5]  += sy * dz;
            v[6]  += sz * dx;  v[7]  += sz * dy;  v[8]  += sz * dz;
            v[9]  += sx;  v[10] += sy;  v[11] += sz;
            v[12] += dx;  v[13] += dy;  v[14] += dz;
            v[15] += sx * sx + sy * sy + sz * sz + dx * dx + dy * dy + dz * dz;
        }
    }

    // 64-lane butterfly reduction
    #pragma unroll
    for (int i = 0; i < 16; ++i) {
        #pragma unroll
        for (int mask = 32; mask > 0; mask >>= 1) {
            v[i] += __shfl_xor(v[i], mask);
        }
    }

    if (lane == 0) {
        float4* p = (float4*)(partial + (size_t)b * 16);
        p[0] = make_float4(v[0],  v[1],  v[2],  v[3]);
        p[1] = make_float4(v[4],  v[5],  v[6],  v[7]);
        p[2] = make_float4(v[8],  v[9],  v[10], v[11]);
        p[3] = make_float4(v[12], v[13], v[14], v[15]);
    }
}

// ---------------- Kernel 2: per-element epilogue ----------------
// One thread per batch element; fully parallel f64 Cardano eigen-solve.
__global__ __launch_bounds__(TPB) void kabsch_epilogue_kernel(
    const float* __restrict__ partial,
    const int* __restrict__ num_atoms,
    float* __restrict__ out,
    int B)
{
    const int b = blockIdx.x * TPB + threadIdx.x;
    if (b >= B) return;

    const float4* p = (const float4*)(partial + (size_t)b * 16);
    const float4 r0 = p[0], r1 = p[1], r2 = p[2], r3 = p[3];
    float v[16] = { r0.x, r0.y, r0.z, r0.w,
                    r1.x, r1.y, r1.z, r1.w,
                    r2.x, r2.y, r2.z, r2.w,
                    r3.x, r3.y, r3.z, r3.w };

    const int na = num_atoms[b];
    const double n = (double)na;
    const double sx = (double)v[9],  sy = (double)v[10], sz = (double)v[11];
    const double tx = (double)v[12], ty = (double)v[13], tz = (double)v[14];

    double R[3][3];
    R[0][0] = (double)v[0] - sx * tx / n;
    R[0][1] = (double)v[1] - sx * ty / n;
    R[0][2] = (double)v[2] - sx * tz / n;
    R[1][0] = (double)v[3] - sy * tx / n;
    R[1][1] = (double)v[4] - sy * ty / n;
    R[1][2] = (double)v[5] - sy * tz / n;
    R[2][0] = (double)v[6] - sz * tx / n;
    R[2][1] = (double)v[7] - sz * ty / n;
    R[2][2] = (double)v[8] - sz * tz / n;

    const double sq = (double)v[15] - (sx * sx + sy * sy + sz * sz
                                     + tx * tx + ty * ty + tz * tz) / n;

    const double detR =
        R[0][0] * (R[1][1] * R[2][2] - R[1][2] * R[2][1])
      - R[0][1] * (R[1][0] * R[2][2] - R[1][2] * R[2][0])
      + R[0][2] * (R[1][0] * R[2][1] - R[1][1] * R[2][0]);

    double A00 = R[0][0]*R[0][0] + R[1][0]*R[1][0] + R[2][0]*R[2][0];
    double A11 = R[0][1]*R[0][1] + R[1][1]*R[1][1] + R[2][1]*R[2][1];
    double A22 = R[0][2]*R[0][2] + R[1][2]*R[1][2] + R[2][2]*R[2][2];
    double A01 = R[0][0]*R[0][1] + R[1][0]*R[1][1] + R[2][0]*R[2][1];
    double A02 = R[0][0]*R[0][2] + R[1][0]*R[1][2] + R[2][0]*R[2][2];
    double A12 = R[0][1]*R[0][2] + R[1][1]*R[1][2] + R[2][1]*R[2][2];

    double e0, e1, e2;  // descending
    const double p1 = A01*A01 + A02*A02 + A12*A12;
    if (p1 < 1e-30) {
        e0 = A00; e1 = A11; e2 = A22;
        double tmp;
        if (e0 < e1) { tmp = e0; e0 = e1; e1 = tmp; }
        if (e1 < e2) { tmp = e1; e1 = e2; e2 = tmp; }
        if (e0 < e1) { tmp = e0; e0 = e1; e1 = tmp; }
    } else {
        const double q  = (A00 + A11 + A22) / 3.0;
        const double b00 = A00 - q, b11 = A11 - q, b22 = A22 - q;
        const double p2 = b00*b00 + b11*b11 + b22*b22 + 2.0 * p1;
        const double pp = sqrt(p2 / 6.0);
        const double ip = 1.0 / pp;
        const double B00 = b00*ip, B11 = b11*ip, B22 = b22*ip;
        const double B01 = A01*ip, B02 = A02*ip, B12 = A12*ip;
        double r = 0.5 * (B00 * (B11 * B22 - B12 * B12)
                        - B01 * (B01 * B22 - B12 * B02)
                        + B02 * (B01 * B12 - B11 * B02));
        if (r < -1.0) r = -1.0;
        if (r >  1.0) r =  1.0;
        const double phi = acos(r) / 3.0;
        e0 = q + 2.0 * pp * cos(phi);
        e2 = q + 2.0 * pp * cos(phi + 2.0943951023931953);  // +2pi/3
        e1 = 3.0 * q - e0 - e2;
    }

    const double S0 = sqrt(e0 > 0.0 ? e0 : 0.0);
    const double S1 = sqrt(e1 > 0.0 ? e1 : 0.0);
    const double S2 = sqrt(e2 > 0.0 ? e2 : 0.0);
    const double dsgn = (detR > 0.0) ? 1.0 : ((detR < 0.0) ? -1.0 : 0.0);
    const double trace_opt = S0 + S1 + dsgn * S2;

    double msd = (sq - 2.0 * trace_opt) / n;
    if (msd < 0.0) msd = 0.0;
    out[b] = (float)sqrt(msd);
}

extern "C" void kernel_launch(void* const* d_in, const int* in_sizes, int n_in,
                              void* d_out, int out_size, void* d_ws, size_t ws_size,
                              hipStream_t stream) {
    const float* inp = (const float*)d_in[0];
    const float* tgt = (const float*)d_in[1];
    const int* num_atoms = (const int*)d_in[2];
    float* out = (float*)d_out;
    float* partial = (float*)d_ws;  // B*16 floats = 512 KB

    const int B = in_sizes[0] / FPE;
    const int blocks1 = (B + WPB - 1) / WPB;
    kabsch_reduce_kernel<<<blocks1, TPB, 0, stream>>>(inp, tgt, num_atoms, partial, B);
    const int blocks2 = (B + TPB - 1) / TPB;
    kabsch_epilogue_kernel<<<blocks2, TPB, 0, stream>>>(partial, num_atoms, out, B);
}

// Round 7
// 119.487 us; speedup vs baseline: 1.3145x; 1.3145x over previous
//
#include <hip/hip_runtime.h>
#include <math.h>

#define NATOMS 512
#define TPB 256
#define WPB 4                 // waves per block; one wave = one batch element
#define FPE (3 * NATOMS)      // 1536 floats per element per array
#define LDSF (2 * FPE)        // 3072 floats of LDS per wave (src + dst)

// Async global->LDS DMA, 16 B per lane, LDS dest = uniform base + lane*16.
__device__ __forceinline__ void async_copy16(const float* g, float* l) {
    __builtin_amdgcn_global_load_lds(
        (const __attribute__((address_space(1))) void*)g,
        (__attribute__((address_space(3))) void*)l,
        16, 0, 0);
}

// ---------------- Kernel 1: streaming reduction ----------------
// One wave per element. Stage the element's src (6 KB) + dst (6 KB) into
// wave-private LDS with 12 global_load_lds_dwordx4 (no VGPR round-trip,
// 12 KB in flight per wave), one wave-local vmcnt(0), then per-atom LDS
// reads (12 B lane stride -> 2 lanes/bank, conflict-free on wave64).
// NOTE: no __launch_bounds__ min-waves — round 6 showed forcing 8 w/EU
// squeezes VGPR to 32 and spills (WRITE_SIZE 80 MB, 63 us). LDS (48 KB)
// is the intended occupancy limiter here (3 blocks/CU).
__global__ __launch_bounds__(TPB) void kabsch_reduce_kernel(
    const float* __restrict__ inp,
    const float* __restrict__ tgt,
    const int* __restrict__ num_atoms,
    float* __restrict__ partial,   // [B][16]
    int B)
{
    __shared__ float lds[WPB * LDSF];   // 48 KB

    const int wave = threadIdx.x >> 6;
    const int lane = threadIdx.x & 63;
    const int b = blockIdx.x * WPB + wave;
    if (b >= B) return;

    const int na = num_atoms[b];
    const float* gs = inp + (size_t)b * FPE;
    const float* gd = tgt + (size_t)b * FPE;
    float* myLds = lds + wave * LDSF;   // [0,1536)=src, [1536,3072)=dst

    // Issue all 12 DMAs back-to-back: 12 KB in flight, zero VGPR cost.
    #pragma unroll
    for (int i = 0; i < 6; ++i)
        async_copy16(gs + i * 256 + lane * 4, myLds + i * 256);
    #pragma unroll
    for (int i = 0; i < 6; ++i)
        async_copy16(gd + i * 256 + lane * 4, myLds + FPE + i * 256);

    // Wave-local wait: vmcnt(0), ignore expcnt/lgkmcnt. No barrier needed —
    // this wave's LDS region is private. Compiler fence stops ds_read hoisting.
    __builtin_amdgcn_s_waitcnt(0x0f70);
    asm volatile("" ::: "memory");

    float v[16];
    #pragma unroll
    for (int i = 0; i < 16; ++i) v[i] = 0.f;

    #pragma unroll
    for (int k = 0; k < 8; ++k) {
        const int atom = 64 * k + lane;
        const int off = 3 * atom;
        const float m = (atom < na) ? 1.f : 0.f;
        const float sx = myLds[off]           * m;
        const float sy = myLds[off + 1]       * m;
        const float sz = myLds[off + 2]       * m;
        const float dx = myLds[FPE + off]     * m;
        const float dy = myLds[FPE + off + 1] * m;
        const float dz = myLds[FPE + off + 2] * m;
        v[0]  += sx * dx;  v[1]  += sx * dy;  v[2]  += sx * dz;
        v[3]  += sy * dx;  v[4]  += sy * dy;  v[5]  += sy * dz;
        v[6]  += sz * dx;  v[7]  += sz * dy;  v[8]  += sz * dz;
        v[9]  += sx;  v[10] += sy;  v[11] += sz;
        v[12] += dx;  v[13] += dy;  v[14] += dz;
        v[15] += sx * sx + sy * sy + sz * sz + dx * dx + dy * dy + dz * dz;
    }

    // 64-lane butterfly reduction
    #pragma unroll
    for (int i = 0; i < 16; ++i) {
        #pragma unroll
        for (int mask = 32; mask > 0; mask >>= 1) {
            v[i] += __shfl_xor(v[i], mask);
        }
    }

    if (lane == 0) {
        float4* p = (float4*)(partial + (size_t)b * 16);
        p[0] = make_float4(v[0],  v[1],  v[2],  v[3]);
        p[1] = make_float4(v[4],  v[5],  v[6],  v[7]);
        p[2] = make_float4(v[8],  v[9],  v[10], v[11]);
        p[3] = make_float4(v[12], v[13], v[14], v[15]);
    }
}

// ---------------- Kernel 2: per-element epilogue ----------------
// One thread per batch element; fully parallel f64 Cardano eigen-solve.
__global__ __launch_bounds__(TPB) void kabsch_epilogue_kernel(
    const float* __restrict__ partial,
    const int* __restrict__ num_atoms,
    float* __restrict__ out,
    int B)
{
    const int b = blockIdx.x * TPB + threadIdx.x;
    if (b >= B) return;

    const float4* p = (const float4*)(partial + (size_t)b * 16);
    const float4 r0 = p[0], r1 = p[1], r2 = p[2], r3 = p[3];
    float v[16] = { r0.x, r0.y, r0.z, r0.w,
                    r1.x, r1.y, r1.z, r1.w,
                    r2.x, r2.y, r2.z, r2.w,
                    r3.x, r3.y, r3.z, r3.w };

    const int na = num_atoms[b];
    const double n = (double)na;
    const double sx = (double)v[9],  sy = (double)v[10], sz = (double)v[11];
    const double tx = (double)v[12], ty = (double)v[13], tz = (double)v[14];

    double R[3][3];
    R[0][0] = (double)v[0] - sx * tx / n;
    R[0][1] = (double)v[1] - sx * ty / n;
    R[0][2] = (double)v[2] - sx * tz / n;
    R[1][0] = (double)v[3] - sy * tx / n;
    R[1][1] = (double)v[4] - sy * ty / n;
    R[1][2] = (double)v[5] - sy * tz / n;
    R[2][0] = (double)v[6] - sz * tx / n;
    R[2][1] = (double)v[7] - sz * ty / n;
    R[2][2] = (double)v[8] - sz * tz / n;

    const double sq = (double)v[15] - (sx * sx + sy * sy + sz * sz
                                     + tx * tx + ty * ty + tz * tz) / n;

    const double detR =
        R[0][0] * (R[1][1] * R[2][2] - R[1][2] * R[2][1])
      - R[0][1] * (R[1][0] * R[2][2] - R[1][2] * R[2][0])
      + R[0][2] * (R[1][0] * R[2][1] - R[1][1] * R[2][0]);

    double A00 = R[0][0]*R[0][0] + R[1][0]*R[1][0] + R[2][0]*R[2][0];
    double A11 = R[0][1]*R[0][1] + R[1][1]*R[1][1] + R[2][1]*R[2][1];
    double A22 = R[0][2]*R[0][2] + R[1][2]*R[1][2] + R[2][2]*R[2][2];
    double A01 = R[0][0]*R[0][1] + R[1][0]*R[1][1] + R[2][0]*R[2][1];
    double A02 = R[0][0]*R[0][2] + R[1][0]*R[1][2] + R[2][0]*R[2][2];
    double A12 = R[0][1]*R[0][2] + R[1][1]*R[1][2] + R[2][1]*R[2][2];

    double e0, e1, e2;  // descending
    const double p1 = A01*A01 + A02*A02 + A12*A12;
    if (p1 < 1e-30) {
        e0 = A00; e1 = A11; e2 = A22;
        double tmp;
        if (e0 < e1) { tmp = e0; e0 = e1; e1 = tmp; }
        if (e1 < e2) { tmp = e1; e1 = e2; e2 = tmp; }
        if (e0 < e1) { tmp = e0; e0 = e1; e1 = tmp; }
    } else {
        const double q  = (A00 + A11 + A22) / 3.0;
        const double b00 = A00 - q, b11 = A11 - q, b22 = A22 - q;
        const double p2 = b00*b00 + b11*b11 + b22*b22 + 2.0 * p1;
        const double pp = sqrt(p2 / 6.0);
        const double ip = 1.0 / pp;
        const double B00 = b00*ip, B11 = b11*ip, B22 = b22*ip;
        const double B01 = A01*ip, B02 = A02*ip, B12 = A12*ip;
        double r = 0.5 * (B00 * (B11 * B22 - B12 * B12)
                        - B01 * (B01 * B22 - B12 * B02)
                        + B02 * (B01 * B12 - B11 * B02));
        if (r < -1.0) r = -1.0;
        if (r >  1.0) r =  1.0;
        const double phi = acos(r) / 3.0;
        e0 = q + 2.0 * pp * cos(phi);
        e2 = q + 2.0 * pp * cos(phi + 2.0943951023931953);  // +2pi/3
        e1 = 3.0 * q - e0 - e2;
    }

    const double S0 = sqrt(e0 > 0.0 ? e0 : 0.0);
    const double S1 = sqrt(e1 > 0.0 ? e1 : 0.0);
    const double S2 = sqrt(e2 > 0.0 ? e2 : 0.0);
    const double dsgn = (detR > 0.0) ? 1.0 : ((detR < 0.0) ? -1.0 : 0.0);
    const double trace_opt = S0 + S1 + dsgn * S2;

    double msd = (sq - 2.0 * trace_opt) / n;
    if (msd < 0.0) msd = 0.0;
    out[b] = (float)sqrt(msd);
}

extern "C" void kernel_launch(void* const* d_in, const int* in_sizes, int n_in,
                              void* d_out, int out_size, void* d_ws, size_t ws_size,
                              hipStream_t stream) {
    const float* inp = (const float*)d_in[0];
    const float* tgt = (const float*)d_in[1];
    const int* num_atoms = (const int*)d_in[2];
    float* out = (float*)d_out;
    float* partial = (float*)d_ws;  // B*16 floats = 512 KB

    const int B = in_sizes[0] / FPE;
    const int blocks1 = (B + WPB - 1) / WPB;
    kabsch_reduce_kernel<<<blocks1, TPB, 0, stream>>>(inp, tgt, num_atoms, partial, B);
    const int blocks2 = (B + TPB - 1) / TPB;
    kabsch_epilogue_kernel<<<blocks2, TPB, 0, stream>>>(partial, num_atoms, out, B);
}

// Round 9
// 116.815 us; speedup vs baseline: 1.3446x; 1.0229x over previous
//
#include <hip/hip_runtime.h>
#include <math.h>

#define NATOMS 512
#define TPB 256
#define WPB 4                 // waves per block; one wave = one batch element
#define FPE (3 * NATOMS)      // 1536 floats per element per array
#define LDSF (2 * FPE)        // 3072 floats of LDS per wave (src + dst)

// Async global->LDS DMA, 16 B per lane, LDS dest = uniform base + lane*16.
__device__ __forceinline__ void async_copy16(const float* g, float* l) {
    __builtin_amdgcn_global_load_lds(
        (const __attribute__((address_space(1))) void*)g,
        (__attribute__((address_space(3))) void*)l,
        16, 0, 0);
}

// DPP-based 64-lane sum on the VALU pipe (no LDS-pipe traffic, no lgkmcnt).
// dpp_ctrl must be an immediate -> template parameter.
// Sequence: row_shr 1/2/4/8 (row totals at lanes 15/31/47/63), row_bcast:15
// (lane31 += lane15; lane63 += lane47), row_bcast:31 (lane63 += lane31)
// -> full wave sum in lane 63. bound_ctrl=true: invalid source reads 0.
template <int CTRL>
__device__ __forceinline__ float dpp_add(float x) {
    const int yi = __builtin_amdgcn_update_dpp(
        0, __float_as_int(x), CTRL, 0xf, 0xf, true);
    return x + __int_as_float(yi);
}
__device__ __forceinline__ float wave_sum63(float x) {
    x = dpp_add<0x111>(x);  // row_shr:1
    x = dpp_add<0x112>(x);  // row_shr:2
    x = dpp_add<0x114>(x);  // row_shr:4
    x = dpp_add<0x118>(x);  // row_shr:8
    x = dpp_add<0x142>(x);  // row_bcast:15
    x = dpp_add<0x143>(x);  // row_bcast:31
    return x;               // lane 63 holds the wave total
}

// ---------------- Kernel 1: streaming reduction ----------------
// One wave per element. Stage src (6 KB) + dst (6 KB) into wave-private LDS
// via 12 global_load_lds_dwordx4 (12 KB in flight, zero VGPR cost), one
// wave-local vmcnt(0), per-atom LDS reads (12 B lane stride, 2 lanes/bank =
// free), then a DPP (VALU-pipe) wave reduction — the shfl butterfly was
// ~96 LDS-pipe swizzles/wave, contending with ds_reads across 32 waves/CU.
__global__ __launch_bounds__(TPB) void kabsch_reduce_kernel(
    const float* __restrict__ inp,
    const float* __restrict__ tgt,
    const int* __restrict__ num_atoms,
    float* __restrict__ partial,   // [B][16]
    int B)
{
    __shared__ float lds[WPB * LDSF];   // 48 KB

    const int wave = threadIdx.x >> 6;
    const int lane = threadIdx.x & 63;
    const int b = blockIdx.x * WPB + wave;
    if (b >= B) return;

    const int na = num_atoms[b];
    const float* gs = inp + (size_t)b * FPE;
    const float* gd = tgt + (size_t)b * FPE;
    float* myLds = lds + wave * LDSF;   // [0,1536)=src, [1536,3072)=dst

    #pragma unroll
    for (int i = 0; i < 6; ++i)
        async_copy16(gs + i * 256 + lane * 4, myLds + i * 256);
    #pragma unroll
    for (int i = 0; i < 6; ++i)
        async_copy16(gd + i * 256 + lane * 4, myLds + FPE + i * 256);

    // Wave-local wait: vmcnt(0) only (LDS region is wave-private, no barrier).
    __builtin_amdgcn_s_waitcnt(0x0f70);
    asm volatile("" ::: "memory");

    float v[16];
    #pragma unroll
    for (int i = 0; i < 16; ++i) v[i] = 0.f;

    #pragma unroll
    for (int k = 0; k < 8; ++k) {
        const int atom = 64 * k + lane;
        const int off = 3 * atom;
        const float m = (atom < na) ? 1.f : 0.f;
        const float sx = myLds[off]           * m;
        const float sy = myLds[off + 1]       * m;
        const float sz = myLds[off + 2]       * m;
        const float dx = myLds[FPE + off]     * m;
        const float dy = myLds[FPE + off + 1] * m;
        const float dz = myLds[FPE + off + 2] * m;
        v[0]  += sx * dx;  v[1]  += sx * dy;  v[2]  += sx * dz;
        v[3]  += sy * dx;  v[4]  += sy * dy;  v[5]  += sy * dz;
        v[6]  += sz * dx;  v[7]  += sz * dy;  v[8]  += sz * dz;
        v[9]  += sx;  v[10] += sy;  v[11] += sz;
        v[12] += dx;  v[13] += dy;  v[14] += dz;
        v[15] += sx * sx + sy * sy + sz * sz + dx * dx + dy * dy + dz * dz;
    }

    // VALU-pipe wave reduction; totals valid in lane 63.
    #pragma unroll
    for (int i = 0; i < 16; ++i) v[i] = wave_sum63(v[i]);

    if (lane == 63) {
        float4* p = (float4*)(partial + (size_t)b * 16);
        p[0] = make_float4(v[0],  v[1],  v[2],  v[3]);
        p[1] = make_float4(v[4],  v[5],  v[6],  v[7]);
        p[2] = make_float4(v[8],  v[9],  v[10], v[11]);
        p[3] = make_float4(v[12], v[13], v[14], v[15]);
    }
}

// ---------------- Kernel 2: per-element epilogue ----------------
// One thread per batch element; fully parallel f64 Cardano eigen-solve.
__global__ __launch_bounds__(TPB) void kabsch_epilogue_kernel(
    const float* __restrict__ partial,
    const int* __restrict__ num_atoms,
    float* __restrict__ out,
    int B)
{
    const int b = blockIdx.x * TPB + threadIdx.x;
    if (b >= B) return;

    const float4* p = (const float4*)(partial + (size_t)b * 16);
    const float4 r0 = p[0], r1 = p[1], r2 = p[2], r3 = p[3];
    float v[16] = { r0.x, r0.y, r0.z, r0.w,
                    r1.x, r1.y, r1.z, r1.w,
                    r2.x, r2.y, r2.z, r2.w,
                    r3.x, r3.y, r3.z, r3.w };

    const int na = num_atoms[b];
    const double n = (double)na;
    const double sx = (double)v[9],  sy = (double)v[10], sz = (double)v[11];
    const double tx = (double)v[12], ty = (double)v[13], tz = (double)v[14];

    double R[3][3];
    R[0][0] = (double)v[0] - sx * tx / n;
    R[0][1] = (double)v[1] - sx * ty / n;
    R[0][2] = (double)v[2] - sx * tz / n;
    R[1][0] = (double)v[3] - sy * tx / n;
    R[1][1] = (double)v[4] - sy * ty / n;
    R[1][2] = (double)v[5] - sy * tz / n;
    R[2][0] = (double)v[6] - sz * tx / n;
    R[2][1] = (double)v[7] - sz * ty / n;
    R[2][2] = (double)v[8] - sz * tz / n;

    const double sq = (double)v[15] - (sx * sx + sy * sy + sz * sz
                                     + tx * tx + ty * ty + tz * tz) / n;

    const double detR =
        R[0][0] * (R[1][1] * R[2][2] - R[1][2] * R[2][1])
      - R[0][1] * (R[1][0] * R[2][2] - R[1][2] * R[2][0])
      + R[0][2] * (R[1][0] * R[2][1] - R[1][1] * R[2][0]);

    double A00 = R[0][0]*R[0][0] + R[1][0]*R[1][0] + R[2][0]*R[2][0];
    double A11 = R[0][1]*R[0][1] + R[1][1]*R[1][1] + R[2][1]*R[2][1];
    double A22 = R[0][2]*R[0][2] + R[1][2]*R[1][2] + R[2][2]*R[2][2];
    double A01 = R[0][0]*R[0][1] + R[1][0]*R[1][1] + R[2][0]*R[2][1];
    double A02 = R[0][0]*R[0][2] + R[1][0]*R[1][2] + R[2][0]*R[2][2];
    double A12 = R[0][1]*R[0][2] + R[1][1]*R[1][2] + R[2][1]*R[2][2];

    double e0, e1, e2;  // descending
    const double p1 = A01*A01 + A02*A02 + A12*A12;
    if (p1 < 1e-30) {
        e0 = A00; e1 = A11; e2 = A22;
        double tmp;
        if (e0 < e1) { tmp = e0; e0 = e1; e1 = tmp; }
        if (e1 < e2) { tmp = e1; e1 = e2; e2 = tmp; }
        if (e0 < e1) { tmp = e0; e0 = e1; e1 = tmp; }
    } else {
        const double q  = (A00 + A11 + A22) / 3.0;
        const double b00 = A00 - q, b11 = A11 - q, b22 = A22 - q;
        const double p2 = b00*b00 + b11*b11 + b22*b22 + 2.0 * p1;
        const double pp = sqrt(p2 / 6.0);
        const double ip = 1.0 / pp;
        const double B00 = b00*ip, B11 = b11*ip, B22 = b22*ip;
        const double B01 = A01*ip, B02 = A02*ip, B12 = A12*ip;
        double r = 0.5 * (B00 * (B11 * B22 - B12 * B12)
                        - B01 * (B01 * B22 - B12 * B02)
                        + B02 * (B01 * B12 - B11 * B02));
        if (r < -1.0) r = -1.0;
        if (r >  1.0) r =  1.0;
        const double phi = acos(r) / 3.0;
        e0 = q + 2.0 * pp * cos(phi);
        e2 = q + 2.0 * pp * cos(phi + 2.0943951023931953);  // +2pi/3
        e1 = 3.0 * q - e0 - e2;
    }

    const double S0 = sqrt(e0 > 0.0 ? e0 : 0.0);
    const double S1 = sqrt(e1 > 0.0 ? e1 : 0.0);
    const double S2 = sqrt(e2 > 0.0 ? e2 : 0.0);
    const double dsgn = (detR > 0.0) ? 1.0 : ((detR < 0.0) ? -1.0 : 0.0);
    const double trace_opt = S0 + S1 + dsgn * S2;

    double msd = (sq - 2.0 * trace_opt) / n;
    if (msd < 0.0) msd = 0.0;
    out[b] = (float)sqrt(msd);
}

extern "C" void kernel_launch(void* const* d_in, const int* in_sizes, int n_in,
                              void* d_out, int out_size, void* d_ws, size_t ws_size,
                              hipStream_t stream) {
    const float* inp = (const float*)d_in[0];
    const float* tgt = (const float*)d_in[1];
    const int* num_atoms = (const int*)d_in[2];
    float* out = (float*)d_out;
    float* partial = (float*)d_ws;  // B*16 floats = 512 KB

    const int B = in_sizes[0] / FPE;
    const int blocks1 = (B + WPB - 1) / WPB;
    kabsch_reduce_kernel<<<blocks1, TPB, 0, stream>>>(inp, tgt, num_atoms, partial, B);
    const int blocks2 = (B + TPB - 1) / TPB;
    kabsch_epilogue_kernel<<<blocks2, TPB, 0, stream>>>(partial, num_atoms, out, B);
}